// Round 1
// baseline (1060.299 us; speedup 1.0000x reference)
//
#include <hip/hip_runtime.h>
#include <hip/hip_bf16.h>
#include <cstdint>

// HEARConv: relation-projected edge attention + edge-softmax + weighted aggregation.
// Pipeline: hist -> scan(3 phase) -> scatter(sort by r, CSR by dst) -> score -> aggregate.

__device__ __forceinline__ int rfl(int v) { return __builtin_amdgcn_readfirstlane(v); }

// ---------------- histogram: per-dst counts (global atomics) + per-r counts (LDS-agg) ----------
__global__ void hist_k(const int* __restrict__ dst, const int* __restrict__ rt,
                       int* __restrict__ cnt_dst, int* __restrict__ cnt_r, int E) {
  __shared__ int hr[8];
  int tid = threadIdx.x;
  if (tid < 8) hr[tid] = 0;
  __syncthreads();
  int e = blockIdx.x * blockDim.x + tid;
  if (e < E) {
    atomicAdd(&cnt_dst[dst[e]], 1);
    atomicAdd(&hr[rt[e]], 1);
  }
  __syncthreads();
  if (tid < 8 && hr[tid] > 0) atomicAdd(&cnt_r[tid], hr[tid]);
}

// ---------------- scan phase A: per-1024 block exclusive scan, block totals -> partials --------
__global__ void scan_a(const int* __restrict__ cnt, int* __restrict__ excl_out,
                       int* __restrict__ partials, int n) {
  __shared__ int wsum[16];
  __shared__ int wbase[16];
  int tid = threadIdx.x;
  int g = blockIdx.x * 1024 + tid;
  int v = (g < n) ? cnt[g] : 0;
  int x = v;
#pragma unroll
  for (int off = 1; off < 64; off <<= 1) {
    int y = __shfl_up(x, off);
    if ((tid & 63) >= off) x += y;
  }
  if ((tid & 63) == 63) wsum[tid >> 6] = x;
  __syncthreads();
  if (tid == 0) {
    int run = 0;
#pragma unroll
    for (int w = 0; w < 16; ++w) { wbase[w] = run; run += wsum[w]; }
    partials[blockIdx.x] = run;
  }
  __syncthreads();
  int excl = x - v + wbase[tid >> 6];
  if (g < n) excl_out[g] = excl;
}

// ---------------- scan phase B: serial scan of block partials + the 8 relation counts ----------
__global__ void scan_b(int* __restrict__ partials, int nb,
                       const int* __restrict__ cnt_r, int* __restrict__ offs_r,
                       int* __restrict__ cursor_r) {
  if (threadIdx.x == 0) {
    int run = 0;
    for (int b = 0; b < nb; ++b) { int t = partials[b]; partials[b] = run; run += t; }
    int rr = 0;
    for (int r = 0; r < 8; ++r) { offs_r[r] = rr; cursor_r[r] = rr; rr += cnt_r[r]; }
    offs_r[8] = rr;
  }
}

// ---------------- scan phase C: finalize dst offsets + cursors ---------------------------------
__global__ void scan_c(int* __restrict__ offs, int* __restrict__ cursor,
                       const int* __restrict__ partials, int n, int Etot) {
  int g = blockIdx.x * 1024 + threadIdx.x;
  if (g < n) {
    int o = cursor[g] + partials[blockIdx.x];
    offs[g] = o;
    cursor[g] = o;
  }
  if (g == 0) offs[n] = Etot;
}

// ---------------- scatter: edge ids sorted by relation, and CSR edge list by dst ---------------
__global__ void scatter_k(const int* __restrict__ dst, const int* __restrict__ rt,
                          int* __restrict__ cursor_dst, int* __restrict__ cursor_r,
                          int* __restrict__ eid_dst, int* __restrict__ eid_r, int E) {
  __shared__ int hr[8], baser[8];
  int tid = threadIdx.x;
  if (tid < 8) hr[tid] = 0;
  __syncthreads();
  int e = blockIdx.x * blockDim.x + tid;
  int r = 0, lpos = 0;
  if (e < E) {
    r = rt[e];
    lpos = atomicAdd(&hr[r], 1);
  }
  __syncthreads();
  if (tid < 8) baser[tid] = hr[tid] ? atomicAdd(&cursor_r[tid], hr[tid]) : 0;
  __syncthreads();
  if (e < E) {
    eid_r[baser[r] + lpos] = e;
    int p = atomicAdd(&cursor_dst[dst[e]], 1);
    eid_dst[p] = e;
  }
}

// ---------------- score kernel: one wave per 16 edges (relation-sorted) ------------------------
// lane = output index hk (h*32+k). W columns live in VGPRs, reloaded only when r changes
// (<= 7 bucket boundaries total). feat/qual rows are wave-uniform -> scalar loads.
__global__ __launch_bounds__(256) void score_k(
    const float* __restrict__ feat, const float* __restrict__ qual,
    const float* __restrict__ Wsrc, const float* __restrict__ bsrc,
    const float* __restrict__ Wqual, const float* __restrict__ bqual,
    const float* __restrict__ attn,
    const int* __restrict__ src_idx, const int* __restrict__ nid_idx,
    const int* __restrict__ rt,
    const int* __restrict__ eid_r, float* __restrict__ scores, int E) {
  const int lane = threadIdx.x & 63;
  const int wid = threadIdx.x >> 6;
  const long wave = (long)blockIdx.x * 4 + wid;
  const int base = (int)(wave * 16);
  if (base >= E) return;
  const int cnt = min(16, E - base);

  float wsc[64], wqc[64];
  float bias_l = 0.f, attn_l = 0.f;
  int cur_r = -1;

  for (int i = 0; i < cnt; ++i) {
    const int e = rfl(eid_r[base + i]);
    const int r = rfl(rt[e]);
    if (r != cur_r) {
      cur_r = r;
      const float* Ws = Wsrc + (size_t)r * 4096;
      const float* Wq = Wqual + (size_t)r * 4096;
#pragma unroll
      for (int d = 0; d < 64; ++d) {
        wsc[d] = Ws[d * 64 + lane];
        wqc[d] = Wq[d * 64 + lane];
      }
      bias_l = bsrc[r * 64 + lane] + bqual[r * 64 + lane];
      attn_l = attn[r * 64 + lane];
    }
    const int s = rfl(src_idx[e]);
    const int q = rfl(nid_idx[e]);
    const float4* f4 = reinterpret_cast<const float4*>(feat + (size_t)s * 64);
    const float4* q4 = reinterpret_cast<const float4*>(qual + (size_t)q * 64);
    float a0 = 0.f, a1 = 0.f, a2 = 0.f, a3 = 0.f;
#pragma unroll
    for (int d4 = 0; d4 < 16; ++d4) {
      float4 fv = f4[d4];
      a0 += fv.x * wsc[d4 * 4 + 0];
      a1 += fv.y * wsc[d4 * 4 + 1];
      a2 += fv.z * wsc[d4 * 4 + 2];
      a3 += fv.w * wsc[d4 * 4 + 3];
    }
#pragma unroll
    for (int d4 = 0; d4 < 16; ++d4) {
      float4 qv = q4[d4];
      a0 += qv.x * wqc[d4 * 4 + 0];
      a1 += qv.y * wqc[d4 * 4 + 1];
      a2 += qv.z * wqc[d4 * 4 + 2];
      a3 += qv.w * wqc[d4 * 4 + 3];
    }
    float v = (a0 + a1) + (a2 + a3) + bias_l;
    v = v > 0.f ? v : 0.2f * v;     // leaky_relu, slope 0.2
    float c = v * attn_l;
    // sum over 32 lanes within each half-wave (h0 = lanes 0..31, h1 = lanes 32..63)
#pragma unroll
    for (int off = 1; off < 32; off <<= 1) c += __shfl_xor(c, off);
    float c1 = __shfl(c, 32);
    if (lane == 0) {
      reinterpret_cast<float2*>(scores)[e] = make_float2(c, c1);
    }
  }
}

// ---------------- aggregation: one wave per destination node -----------------------------------
// Phase A: chunked-parallel max over incoming edges. Phase B: sequential edge loop,
// accumulate unnormalized sum(feat*z) and sum(z), divide at the end.
__global__ __launch_bounds__(256) void agg_k(
    const float* __restrict__ feat, const float* __restrict__ scores,
    const int* __restrict__ src_idx,
    const int* __restrict__ offs, const int* __restrict__ eid_dst,
    float* __restrict__ out, int N) {
  const int lane = threadIdx.x & 63;
  const int wid = threadIdx.x >> 6;
  const int n = blockIdx.x * 4 + wid;
  if (n >= N) return;
  const int beg = rfl(offs[n]);
  const int end = rfl(offs[n + 1]);
  const int cnt = end - beg;
  float acc0 = 0.f, acc1 = 0.f;
  if (cnt > 0) {
    float m0 = -3.4e38f, m1 = -3.4e38f;
    for (int i = lane; i < cnt; i += 64) {
      const int e = eid_dst[beg + i];
      const float2 s2 = reinterpret_cast<const float2*>(scores)[e];
      m0 = fmaxf(m0, s2.x);
      m1 = fmaxf(m1, s2.y);
    }
#pragma unroll
    for (int off = 32; off; off >>= 1) {
      m0 = fmaxf(m0, __shfl_xor(m0, off));
      m1 = fmaxf(m1, __shfl_xor(m1, off));
    }
    float d0 = 0.f, d1 = 0.f;
    for (int i = 0; i < cnt; ++i) {
      const int e = rfl(eid_dst[beg + i]);
      const float2 s2 = reinterpret_cast<const float2*>(scores)[e];
      const float z0 = __expf(s2.x - m0);
      const float z1 = __expf(s2.y - m1);
      d0 += z0;
      d1 += z1;
      const int s = rfl(src_idx[e]);
      const float f = feat[(size_t)s * 64 + lane];
      acc0 += f * z0;
      acc1 += f * z1;
    }
    acc0 /= d0;
    acc1 /= d1;
  }
  out[(size_t)n * 128 + lane] = acc0;
  out[(size_t)n * 128 + 64 + lane] = acc1;
}

extern "C" void kernel_launch(void* const* d_in, const int* in_sizes, int n_in,
                              void* d_out, int out_size, void* d_ws, size_t ws_size,
                              hipStream_t stream) {
  const float* feat  = (const float*)d_in[0];
  const float* Wsrc  = (const float*)d_in[1];
  const float* bsrc  = (const float*)d_in[2];
  const float* qual  = (const float*)d_in[3];
  const float* Wqual = (const float*)d_in[4];
  const float* bqual = (const float*)d_in[5];
  const float* attn  = (const float*)d_in[6];
  const int* src = (const int*)d_in[7];
  const int* dst = (const int*)d_in[8];
  const int* rt  = (const int*)d_in[9];
  const int* nid = (const int*)d_in[10];
  float* out = (float*)d_out;

  const int N = in_sizes[0] / 64;
  const int E = in_sizes[7];
  const int nb = (N + 1023) / 1024;

  char* p = (char*)d_ws;
  int* cnt_dst = (int*)p;      p += (size_t)N * 4;
  int* cnt_r = (int*)p;        p += 16 * 4;          // contiguous with cnt_dst for one memset
  int* offs_dst = (int*)p;     p += (size_t)(N + 1) * 4;
  int* cursor_dst = (int*)p;   p += (size_t)N * 4;
  int* offs_r = (int*)p;       p += 16 * 4;
  int* cursor_r = (int*)p;     p += 16 * 4;
  int* partials = (int*)p;     p += (size_t)((nb + 15) & ~15) * 4;
  int* eid_r = (int*)p;        p += (size_t)E * 4;
  int* eid_dst = (int*)p;      p += (size_t)E * 4;
  float* scores = (float*)p;   p += (size_t)E * 2 * 4;
  if ((size_t)(p - (char*)d_ws) > ws_size) return;   // workspace too small: bail visibly

  hipMemsetAsync(cnt_dst, 0, (size_t)(N + 16) * 4, stream);

  hist_k<<<(E + 1023) / 1024, 1024, 0, stream>>>(dst, rt, cnt_dst, cnt_r, E);
  scan_a<<<nb, 1024, 0, stream>>>(cnt_dst, cursor_dst, partials, N);
  scan_b<<<1, 64, 0, stream>>>(partials, nb, cnt_r, offs_r, cursor_r);
  scan_c<<<nb, 1024, 0, stream>>>(offs_dst, cursor_dst, partials, N, E);
  scatter_k<<<(E + 1023) / 1024, 1024, 0, stream>>>(dst, rt, cursor_dst, cursor_r,
                                                    eid_dst, eid_r, E);
  score_k<<<(E + 63) / 64, 256, 0, stream>>>(feat, qual, Wsrc, bsrc, Wqual, bqual, attn,
                                             src, nid, rt, eid_r, scores, E);
  agg_k<<<(N + 3) / 4, 256, 0, stream>>>(feat, scores, src, offs_dst, eid_dst, out, N);
}

// Round 2
// 294.585 us; speedup vs baseline: 3.5993x; 3.5993x over previous
//
#include <hip/hip_runtime.h>
#include <hip/hip_bf16.h>
#include <cstdint>

// HEARConv: relation-projected edge attention + edge-softmax + weighted aggregation.
// Pipeline: hist -> scan(3 phase) -> scatter(sort by r padded, CSR by dst) -> score(MFMA) -> agg.

__device__ __forceinline__ int rfl(int v) { return __builtin_amdgcn_readfirstlane(v); }

typedef __attribute__((ext_vector_type(8))) short bf16x8;
typedef __attribute__((ext_vector_type(4))) float f32x4;

__device__ __forceinline__ ushort bf16r(float x) {   // f32 -> bf16, round-nearest-even
  union { float f; uint32_t u; } c{x};
  uint32_t u = c.u + 0x7fffu + ((c.u >> 16) & 1u);
  return (ushort)(u >> 16);
}
__device__ __forceinline__ uint32_t pk2(float a, float b) {
  return (uint32_t)bf16r(a) | ((uint32_t)bf16r(b) << 16);
}

// ---------------- histogram: per-dst counts (global atomics) + per-r counts (LDS-agg) ----------
__global__ void hist_k(const int* __restrict__ dst, const int* __restrict__ rt,
                       int* __restrict__ cnt_dst, int* __restrict__ cnt_r, int E) {
  __shared__ int hr[8];
  int tid = threadIdx.x;
  if (tid < 8) hr[tid] = 0;
  __syncthreads();
  int e = blockIdx.x * blockDim.x + tid;
  if (e < E) {
    atomicAdd(&cnt_dst[dst[e]], 1);
    atomicAdd(&hr[rt[e]], 1);
  }
  __syncthreads();
  if (tid < 8 && hr[tid] > 0) atomicAdd(&cnt_r[tid], hr[tid]);
}

// ---------------- scan phase A: per-1024 block exclusive scan, block totals -> partials --------
__global__ void scan_a(const int* __restrict__ cnt, int* __restrict__ excl_out,
                       int* __restrict__ partials, int n) {
  __shared__ int wsum[16];
  __shared__ int wbase[16];
  int tid = threadIdx.x;
  int g = blockIdx.x * 1024 + tid;
  int v = (g < n) ? cnt[g] : 0;
  int x = v;
#pragma unroll
  for (int off = 1; off < 64; off <<= 1) {
    int y = __shfl_up(x, off);
    if ((tid & 63) >= off) x += y;
  }
  if ((tid & 63) == 63) wsum[tid >> 6] = x;
  __syncthreads();
  if (tid == 0) {
    int run = 0;
#pragma unroll
    for (int w = 0; w < 16; ++w) { wbase[w] = run; run += wsum[w]; }
    partials[blockIdx.x] = run;
  }
  __syncthreads();
  int excl = x - v + wbase[tid >> 6];
  if (g < n) excl_out[g] = excl;
}

// ---------------- scan phase B: serial scan of block partials + padded relation offsets --------
__global__ void scan_b(int* __restrict__ partials, int nb,
                       const int* __restrict__ cnt_r, int* __restrict__ poffs,
                       int* __restrict__ cursor_r) {
  if (threadIdx.x == 0) {
    int run = 0;
    for (int b = 0; b < nb; ++b) { int t = partials[b]; partials[b] = run; run += t; }
    int pp = 0;
    for (int r = 0; r < 8; ++r) {
      poffs[r] = pp;
      cursor_r[r] = pp;
      pp += (cnt_r[r] + 127) & ~127;      // pad each bucket to a 128-edge multiple
    }
    poffs[8] = pp;
  }
}

// ---------------- scan phase C: finalize dst offsets + cursors ---------------------------------
__global__ void scan_c(int* __restrict__ offs, int* __restrict__ cursor,
                       const int* __restrict__ partials, int n, int Etot) {
  int g = blockIdx.x * 1024 + threadIdx.x;
  if (g < n) {
    int o = cursor[g] + partials[blockIdx.x];
    offs[g] = o;
    cursor[g] = o;
  }
  if (g == 0) offs[n] = Etot;
}

// ---------------- scatter: edge ids sorted by relation (padded), and CSR edge list by dst ------
__global__ void scatter_k(const int* __restrict__ dst, const int* __restrict__ rt,
                          int* __restrict__ cursor_dst, int* __restrict__ cursor_r,
                          int* __restrict__ eid_dst, int* __restrict__ eid_r, int E) {
  __shared__ int hr[8], baser[8];
  int tid = threadIdx.x;
  if (tid < 8) hr[tid] = 0;
  __syncthreads();
  int e = blockIdx.x * blockDim.x + tid;
  int r = 0, lpos = 0;
  if (e < E) {
    r = rt[e];
    lpos = atomicAdd(&hr[r], 1);
  }
  __syncthreads();
  if (tid < 8) baser[tid] = hr[tid] ? atomicAdd(&cursor_r[tid], hr[tid]) : 0;
  __syncthreads();
  if (e < E) {
    eid_r[baser[r] + lpos] = e;
    int p = atomicAdd(&cursor_dst[dst[e]], 1);
    eid_dst[p] = e;
  }
}

// ---------------- score kernel: MFMA gather-GEMM over relation buckets -------------------------
// Block = 256 threads handles 128 edges of ONE relation (buckets padded, sentinel -1).
// Stage gathered feat/qual rows as bf16 in XOR-swizzled LDS; wave w owns output cols
// [16w,16w+16): W fragments in VGPRs; 4x mfma_16x16x32_bf16 per 16-edge tile; epilogue
// bias+leakyrelu+attn dot, 16-lane shuffle reduce, cross-wave head combine via LDS.
__global__ __launch_bounds__(256) void score_k(
    const float* __restrict__ feat, const float* __restrict__ qual,
    const float* __restrict__ Wsrc, const float* __restrict__ bsrc,
    const float* __restrict__ Wqual, const float* __restrict__ bqual,
    const float* __restrict__ attn,
    const int* __restrict__ src_idx, const int* __restrict__ nid_idx,
    const int* __restrict__ poffs, const int* __restrict__ eid_r,
    float* __restrict__ scores) {
  __shared__ __align__(16) ushort lA[2][128 * 64];   // [feat|qual][edge][k] bf16, 32 KB
  __shared__ float comb[4][128];                     // per-wave partial scores, 2 KB

  const int tid = threadIdx.x;
  const int lane = tid & 63;
  const int wid = tid >> 6;
  const int base = blockIdx.x * 128;
  if (base >= poffs[8]) return;
  int r = 0;
  while (base >= poffs[r + 1]) ++r;

  // ---- stage A: 2 threads per edge slot (each stages half a row of feat and qual) ----
  {
    const int es = tid >> 1;            // edge slot 0..127
    const int hf = tid & 1;             // k half: 0 -> k 0..31, 1 -> k 32..63
    const int eid = eid_r[base + es];
    const int swz = (es & 7) << 4;
    char* dA = (char*)lA[0] + es * 128;
    char* dB = (char*)lA[1] + es * 128;
    if (eid >= 0) {
      const int s = src_idx[eid];
      const int q = nid_idx[eid];
      const float4* fs = (const float4*)(feat + (size_t)s * 64 + hf * 32);
      const float4* fq = (const float4*)(qual + (size_t)q * 64 + hf * 32);
#pragma unroll
      for (int c = 0; c < 4; ++c) {
        float4 v0 = fs[2 * c], v1 = fs[2 * c + 1];
        uint4 pk = make_uint4(pk2(v0.x, v0.y), pk2(v0.z, v0.w),
                              pk2(v1.x, v1.y), pk2(v1.z, v1.w));
        *(uint4*)(dA + ((hf * 64 + c * 16) ^ swz)) = pk;
        float4 w0 = fq[2 * c], w1 = fq[2 * c + 1];
        uint4 pq = make_uint4(pk2(w0.x, w0.y), pk2(w0.z, w0.w),
                              pk2(w1.x, w1.y), pk2(w1.z, w1.w));
        *(uint4*)(dB + ((hf * 64 + c * 16) ^ swz)) = pq;
      }
    } else {
      uint4 z = make_uint4(0, 0, 0, 0);
#pragma unroll
      for (int c = 0; c < 4; ++c) {
        *(uint4*)(dA + ((hf * 64 + c * 16) ^ swz)) = z;
        *(uint4*)(dB + ((hf * 64 + c * 16) ^ swz)) = z;
      }
    }
  }

  // ---- load W fragments (B operand): col = wid*16 + lane&15, k = (lane>>4)*8 + j ----
  const int col = wid * 16 + (lane & 15);
  const int kb = (lane >> 4) * 8;
  bf16x8 wS[2], wQ[2];
#pragma unroll
  for (int s2 = 0; s2 < 2; ++s2) {
#pragma unroll
    for (int j = 0; j < 8; ++j) {
      const int k = s2 * 32 + kb + j;
      wS[s2][j] = (short)bf16r(Wsrc[(size_t)r * 4096 + k * 64 + col]);
      wQ[s2][j] = (short)bf16r(Wqual[(size_t)r * 4096 + k * 64 + col]);
    }
  }
  const float bias_l = bsrc[r * 64 + col] + bqual[r * 64 + col];
  const float attn_l = attn[r * 64 + col];

  __syncthreads();

  // ---- main loop: 8 edge-tiles of 16 ----
#pragma unroll
  for (int et = 0; et < 8; ++et) {
    const int row = et * 16 + (lane & 15);
    const int rb = row * 128;
    const int swz = (row & 7) << 4;
    const int k0 = (lane >> 4) * 16;
    bf16x8 aS0 = *(const bf16x8*)((const char*)lA[0] + rb + (k0 ^ swz));
    bf16x8 aS1 = *(const bf16x8*)((const char*)lA[0] + rb + ((k0 + 64) ^ swz));
    bf16x8 aQ0 = *(const bf16x8*)((const char*)lA[1] + rb + (k0 ^ swz));
    bf16x8 aQ1 = *(const bf16x8*)((const char*)lA[1] + rb + ((k0 + 64) ^ swz));
    f32x4 accS = {0.f, 0.f, 0.f, 0.f}, accQ = {0.f, 0.f, 0.f, 0.f};
    accS = __builtin_amdgcn_mfma_f32_16x16x32_bf16(aS0, wS[0], accS, 0, 0, 0);
    accS = __builtin_amdgcn_mfma_f32_16x16x32_bf16(aS1, wS[1], accS, 0, 0, 0);
    accQ = __builtin_amdgcn_mfma_f32_16x16x32_bf16(aQ0, wQ[0], accQ, 0, 0, 0);
    accQ = __builtin_amdgcn_mfma_f32_16x16x32_bf16(aQ1, wQ[1], accQ, 0, 0, 0);

    // epilogue: D row = (lane>>4)*4 + j (edge), col = lane&15
    float p0, p1, p2, p3;
#pragma unroll
    for (int j = 0; j < 4; ++j) {
      float v = accS[j] + accQ[j] + bias_l;
      v = v > 0.f ? v : 0.2f * v;                 // leaky_relu
      float c = v * attn_l;
      c += __shfl_xor(c, 1);
      c += __shfl_xor(c, 2);
      c += __shfl_xor(c, 4);
      c += __shfl_xor(c, 8);
      if (j == 0) p0 = c; else if (j == 1) p1 = c; else if (j == 2) p2 = c; else p3 = c;
    }
    const int sub = lane & 15;
    if (sub < 4) {
      float v = sub == 0 ? p0 : sub == 1 ? p1 : sub == 2 ? p2 : p3;
      comb[wid][et * 16 + (lane >> 4) * 4 + sub] = v;
    }
  }
  __syncthreads();

  // ---- combine waves into (edge, head) scores; cols 0..31 = h0 (waves 0,1), 32..63 = h1 ----
  {
    const int slot = tid >> 1;
    const int h = tid & 1;
    const int eid = eid_r[base + slot];
    if (eid >= 0) {
      scores[(size_t)eid * 2 + h] = comb[h * 2][slot] + comb[h * 2 + 1][slot];
    }
  }
}

// ---------------- aggregation: one wave per destination node, 4-way unrolled -------------------
__global__ __launch_bounds__(256) void agg_k(
    const float* __restrict__ feat, const float* __restrict__ scores,
    const int* __restrict__ src_idx,
    const int* __restrict__ offs, const int* __restrict__ eid_dst,
    float* __restrict__ out, int N) {
  const int lane = threadIdx.x & 63;
  const int wid = threadIdx.x >> 6;
  const int n = blockIdx.x * 4 + wid;
  if (n >= N) return;
  const int beg = rfl(offs[n]);
  const int end = rfl(offs[n + 1]);
  const int cnt = end - beg;
  float o0 = 0.f, o1 = 0.f;
  if (cnt > 0) {
    const float2* sc2 = (const float2*)scores;
    float m0 = -3.4e38f, m1 = -3.4e38f;
    for (int i = lane; i < cnt; i += 64) {
      const int e = eid_dst[beg + i];
      const float2 s = sc2[e];
      m0 = fmaxf(m0, s.x);
      m1 = fmaxf(m1, s.y);
    }
#pragma unroll
    for (int off = 32; off; off >>= 1) {
      m0 = fmaxf(m0, __shfl_xor(m0, off));
      m1 = fmaxf(m1, __shfl_xor(m1, off));
    }
    float d0 = 0.f, d1 = 0.f;
    float A0 = 0.f, A1 = 0.f, A2 = 0.f, A3 = 0.f;   // head0 accumulators
    float B0 = 0.f, B1 = 0.f, B2 = 0.f, B3 = 0.f;   // head1 accumulators
    for (int i = 0; i < cnt; i += 4) {
      const int eA = rfl(eid_dst[beg + i]);
      const int eB = (i + 1 < cnt) ? rfl(eid_dst[beg + i + 1]) : -1;
      const int eC = (i + 2 < cnt) ? rfl(eid_dst[beg + i + 2]) : -1;
      const int eD = (i + 3 < cnt) ? rfl(eid_dst[beg + i + 3]) : -1;
      const float2 sA = sc2[eA];
      const float2 sB = sc2[eB < 0 ? eA : eB];
      const float2 sC = sc2[eC < 0 ? eA : eC];
      const float2 sD = sc2[eD < 0 ? eA : eD];
      const float fA = feat[(size_t)rfl(src_idx[eA]) * 64 + lane];
      const float fB = feat[(size_t)rfl(src_idx[eB < 0 ? eA : eB]) * 64 + lane];
      const float fC = feat[(size_t)rfl(src_idx[eC < 0 ? eA : eC]) * 64 + lane];
      const float fD = feat[(size_t)rfl(src_idx[eD < 0 ? eA : eD]) * 64 + lane];
      const float zA0 = __expf(sA.x - m0), zA1 = __expf(sA.y - m1);
      const float zB0 = eB >= 0 ? __expf(sB.x - m0) : 0.f;
      const float zB1 = eB >= 0 ? __expf(sB.y - m1) : 0.f;
      const float zC0 = eC >= 0 ? __expf(sC.x - m0) : 0.f;
      const float zC1 = eC >= 0 ? __expf(sC.y - m1) : 0.f;
      const float zD0 = eD >= 0 ? __expf(sD.x - m0) : 0.f;
      const float zD1 = eD >= 0 ? __expf(sD.y - m1) : 0.f;
      d0 += (zA0 + zB0) + (zC0 + zD0);
      d1 += (zA1 + zB1) + (zC1 + zD1);
      A0 += fA * zA0; A1 += fB * zB0; A2 += fC * zC0; A3 += fD * zD0;
      B0 += fA * zA1; B1 += fB * zB1; B2 += fC * zC1; B3 += fD * zD1;
    }
    o0 = ((A0 + A1) + (A2 + A3)) / d0;
    o1 = ((B0 + B1) + (B2 + B3)) / d1;
  }
  out[(size_t)n * 128 + lane] = o0;
  out[(size_t)n * 128 + 64 + lane] = o1;
}

extern "C" void kernel_launch(void* const* d_in, const int* in_sizes, int n_in,
                              void* d_out, int out_size, void* d_ws, size_t ws_size,
                              hipStream_t stream) {
  const float* feat  = (const float*)d_in[0];
  const float* Wsrc  = (const float*)d_in[1];
  const float* bsrc  = (const float*)d_in[2];
  const float* qual  = (const float*)d_in[3];
  const float* Wqual = (const float*)d_in[4];
  const float* bqual = (const float*)d_in[5];
  const float* attn  = (const float*)d_in[6];
  const int* src = (const int*)d_in[7];
  const int* dst = (const int*)d_in[8];
  const int* rt  = (const int*)d_in[9];
  const int* nid = (const int*)d_in[10];
  float* out = (float*)d_out;

  const int N = in_sizes[0] / 64;
  const int E = in_sizes[7];
  const int nb = (N + 1023) / 1024;
  const int EP = E + 1024;                 // padded eid_r capacity

  char* p = (char*)d_ws;
  int* cnt_dst = (int*)p;      p += (size_t)N * 4;
  int* cnt_r = (int*)p;        p += 16 * 4;          // contiguous with cnt_dst for one memset
  int* offs_dst = (int*)p;     p += (size_t)(N + 1) * 4;
  int* cursor_dst = (int*)p;   p += (size_t)N * 4;
  int* poffs = (int*)p;        p += 16 * 4;
  int* cursor_r = (int*)p;     p += 16 * 4;
  int* partials = (int*)p;     p += (size_t)((nb + 15) & ~15) * 4;
  int* eid_r = (int*)p;        p += (size_t)EP * 4;
  int* eid_dst = (int*)p;      p += (size_t)E * 4;
  float* scores = (float*)p;   p += (size_t)E * 2 * 4;
  if ((size_t)(p - (char*)d_ws) > ws_size) return;   // workspace too small: bail visibly

  hipMemsetAsync(cnt_dst, 0, (size_t)(N + 16) * 4, stream);
  hipMemsetAsync(eid_r, 0xFF, (size_t)EP * 4, stream);   // -1 sentinels for bucket padding

  hist_k<<<(E + 1023) / 1024, 1024, 0, stream>>>(dst, rt, cnt_dst, cnt_r, E);
  scan_a<<<nb, 1024, 0, stream>>>(cnt_dst, cursor_dst, partials, N);
  scan_b<<<1, 64, 0, stream>>>(partials, nb, cnt_r, poffs, cursor_r);
  scan_c<<<nb, 1024, 0, stream>>>(offs_dst, cursor_dst, partials, N, E);
  scatter_k<<<(E + 1023) / 1024, 1024, 0, stream>>>(dst, rt, cursor_dst, cursor_r,
                                                    eid_dst, eid_r, E);
  const int NBs = (EP + 127) / 128;
  score_k<<<NBs, 256, 0, stream>>>(feat, qual, Wsrc, bsrc, Wqual, bqual, attn,
                                   src, nid, poffs, eid_r, scores);
  agg_k<<<(N + 3) / 4, 256, 0, stream>>>(feat, scores, src, offs_dst, eid_dst, out, N);
}

// Round 4
// 258.160 us; speedup vs baseline: 4.1071x; 1.1411x over previous
//
#include <hip/hip_runtime.h>
#include <hip/hip_bf16.h>
#include <cstdint>

// HEARConv: relation-projected edge attention + edge-softmax + weighted aggregation.
// Pipeline: hist(+Wtrans) -> scan_a -> scan_b -> scatter(r-sort arrays + dst-sort arrays)
//           -> score(MFMA gather-GEMM) -> agg(lane-parallel softmax-weighted gather).

__device__ __forceinline__ int rfl(int v) { return __builtin_amdgcn_readfirstlane(v); }

typedef __attribute__((ext_vector_type(8))) short bf16x8;
typedef __attribute__((ext_vector_type(4))) float f32x4;

// pack two f32 -> two bf16 (round-half-up; <=1ulp vs RNE, threshold is 4.2e-2)
__device__ __forceinline__ uint32_t pk2(float a, float b) {
  uint32_t ua = __float_as_uint(a) + 0x8000u;
  uint32_t ub = __float_as_uint(b) + 0x8000u;
  return __builtin_amdgcn_perm(ub, ua, 0x07060302u);  // {ua.b2,ua.b3,ub.b2,ub.b3}
}

// sum across each 16-lane row via DPP row_ror (VALU-only, no LDS pipe)
__device__ __forceinline__ float dpp_add16(float x) {
  float s = x;
  int t;
  t = __builtin_amdgcn_update_dpp(0, __float_as_int(s), 0x128, 0xF, 0xF, true);
  s += __int_as_float(t);
  t = __builtin_amdgcn_update_dpp(0, __float_as_int(s), 0x124, 0xF, 0xF, true);
  s += __int_as_float(t);
  t = __builtin_amdgcn_update_dpp(0, __float_as_int(s), 0x122, 0xF, 0xF, true);
  s += __int_as_float(t);
  t = __builtin_amdgcn_update_dpp(0, __float_as_int(s), 0x121, 0xF, 0xF, true);
  s += __int_as_float(t);
  return s;
}

// ---------------- histogram (+ fused W transpose in tail blocks) -------------------------------
// Wt layout: [m][r][col][k] bf16  (m: 0=Wsrc, 1=Wqual), so B-fragments load as 16B vectors.
__global__ void hist_k(const int* __restrict__ dst, const int* __restrict__ rt,
                       int* __restrict__ cnt_dst, int* __restrict__ cnt_r, int E, int histB,
                       const float* __restrict__ Wsrc, const float* __restrict__ Wqual,
                       ushort* __restrict__ Wt) {
  if ((int)blockIdx.x >= histB) {
    const int gt = (blockIdx.x - histB) * 1024 + threadIdx.x;  // 0..4095
    const int m = gt >> 11;
    const int r = (gt >> 8) & 7;
    const int col = (gt >> 2) & 63;
    const int k0 = (gt & 3) * 16;
    const float* W = (m ? Wqual : Wsrc) + (size_t)r * 4096;
    uint32_t o[8];
#pragma unroll
    for (int i = 0; i < 8; ++i) {
      float a = W[(k0 + 2 * i) * 64 + col];
      float b = W[(k0 + 2 * i + 1) * 64 + col];
      o[i] = pk2(a, b);
    }
    ushort* d = Wt + ((((size_t)m * 8 + r) * 64 + col) * 64 + k0);
    *(uint4*)d = make_uint4(o[0], o[1], o[2], o[3]);
    *(uint4*)(d + 8) = make_uint4(o[4], o[5], o[6], o[7]);
    return;
  }
  __shared__ int hr[8];
  int tid = threadIdx.x;
  if (tid < 8) hr[tid] = 0;
  __syncthreads();
  int e = blockIdx.x * blockDim.x + tid;
  if (e < E) {
    atomicAdd(&cnt_dst[dst[e]], 1);
    atomicAdd(&hr[rt[e]], 1);
  }
  __syncthreads();
  if (tid < 8 && hr[tid] > 0) atomicAdd(&cnt_r[tid], hr[tid]);
}

// ---------------- scan phase A: per-1024 block exclusive scan, block totals -> partials --------
__global__ void scan_a(const int* __restrict__ cnt, int* __restrict__ excl,
                       int* __restrict__ cursor, int* __restrict__ partials, int n) {
  __shared__ int wsum[16];
  __shared__ int wbase[16];
  int tid = threadIdx.x;
  int g = blockIdx.x * 1024 + tid;
  int v = (g < n) ? cnt[g] : 0;
  int x = v;
#pragma unroll
  for (int off = 1; off < 64; off <<= 1) {
    int y = __shfl_up(x, off);
    if ((tid & 63) >= off) x += y;
  }
  if ((tid & 63) == 63) wsum[tid >> 6] = x;
  __syncthreads();
  if (tid == 0) {
    int run = 0;
#pragma unroll
    for (int w = 0; w < 16; ++w) { wbase[w] = run; run += wsum[w]; }
    partials[blockIdx.x] = run;
  }
  __syncthreads();
  int ex = x - v + wbase[tid >> 6];
  if (g < n) { excl[g] = ex; cursor[g] = ex; }
}

// ---------------- scan phase B: wave-parallel scan of partials + padded relation offsets -------
__global__ void scan_b(int* __restrict__ partials, int nb,
                       const int* __restrict__ cnt_r, int* __restrict__ poffs,
                       int* __restrict__ cursor_r) {
  const int lane = threadIdx.x;   // 64 threads
  int run = 0;
  for (int b0 = 0; b0 < nb; b0 += 64) {
    int i = b0 + lane;
    int v = (i < nb) ? partials[i] : 0;
    int x = v;
#pragma unroll
    for (int off = 1; off < 64; off <<= 1) {
      int y = __shfl_up(x, off);
      if (lane >= off) x += y;
    }
    if (i < nb) partials[i] = run + x - v;
    run += __shfl(x, 63);
  }
  if (lane == 0) {
    int pp = 0;
    for (int r = 0; r < 8; ++r) {
      poffs[r] = pp;
      cursor_r[r] = pp;
      pp += (cnt_r[r] + 127) & ~127;
    }
    poffs[8] = pp;
  }
}

// ---------------- scatter: r-sorted {src,nid,dpos} arrays + dst-sorted {src} array -------------
__global__ void scatter_k(const int* __restrict__ src, const int* __restrict__ dst,
                          const int* __restrict__ rt, const int* __restrict__ nid,
                          int* __restrict__ cursor_dst, const int* __restrict__ partials,
                          int* __restrict__ cursor_r,
                          int* __restrict__ src_r, int* __restrict__ nid_r,
                          int* __restrict__ dpos_r, int* __restrict__ src_d, int E) {
  __shared__ int hr[8], baser[8];
  int tid = threadIdx.x;
  if (tid < 8) hr[tid] = 0;
  __syncthreads();
  int e = blockIdx.x * blockDim.x + tid;
  int r = 0, lpos = 0;
  if (e < E) {
    r = rt[e];
    lpos = atomicAdd(&hr[r], 1);
  }
  __syncthreads();
  if (tid < 8) baser[tid] = hr[tid] ? atomicAdd(&cursor_r[tid], hr[tid]) : 0;
  __syncthreads();
  if (e < E) {
    const int p_r = baser[r] + lpos;
    const int d = dst[e];
    const int p_d = atomicAdd(&cursor_dst[d], 1) + partials[d >> 10];
    const int s = src[e];
    src_r[p_r] = s;
    nid_r[p_r] = nid[e];
    dpos_r[p_r] = p_d;
    src_d[p_d] = s;
  }
}

// ---------------- score kernel: MFMA gather-GEMM over relation buckets -------------------------
// Block = 256 threads, 128 edges of ONE relation, processed as 2 sub-batches of 64 edges
// through a single 16KB LDS buffer (qual MFMA-accumulates into the same acc as feat).
// 18KB LDS + <=64 VGPR -> 8 blocks/CU target.
__global__ __launch_bounds__(256, 8) void score_k(
    const float* __restrict__ feat, const float* __restrict__ qual,
    const ushort* __restrict__ Wt,
    const float* __restrict__ bsrc, const float* __restrict__ bqual,
    const float* __restrict__ attn,
    const int* __restrict__ src_r, const int* __restrict__ nid_r,
    const int* __restrict__ dpos_r,
    const int* __restrict__ poffs, float* __restrict__ scores2) {
  __shared__ __align__(16) ushort lT[2][64 * 64];   // [feat|qual][edge 0..63][k], 16 KB
  __shared__ float comb[4][128];                    // per-wave partial scores, 2 KB

  const int tid = threadIdx.x;
  const int lane = tid & 63;
  const int wid = tid >> 6;
  const int base = blockIdx.x * 128;
  if (base >= poffs[8]) return;
  int r = 0;
  while (base >= poffs[r + 1]) ++r;

  // B fragments: col = wid*16 + lane&15, k = (lane>>4)*8 + j  (coalesced 16B from Wt)
  const int col = wid * 16 + (lane & 15);
  const int kb = (lane >> 4) * 8;
  const ushort* WtS = Wt + ((size_t)r * 64 + col) * 64;
  const ushort* WtQ = Wt + (((size_t)8 + r) * 64 + col) * 64;
  const bf16x8 wS0 = *(const bf16x8*)(WtS + kb);
  const bf16x8 wS1 = *(const bf16x8*)(WtS + 32 + kb);
  const bf16x8 wQ0 = *(const bf16x8*)(WtQ + kb);
  const bf16x8 wQ1 = *(const bf16x8*)(WtQ + 32 + kb);
  const float bias_l = bsrc[r * 64 + col] + bqual[r * 64 + col];
  const float attn_l = attn[r * 64 + col];

  for (int sb = 0; sb < 2; ++sb) {
    // ---- stage 64 edges (feat + qual halves split across 256 threads) ----
    {
      const int m = tid >> 7;          // 0 = feat, 1 = qual
      const int es = (tid >> 1) & 63;  // edge slot in sub-batch
      const int hf = tid & 1;          // k half
      const int gs = base + sb * 64 + es;
      const int sv = src_r[gs];
      char* dp = (char*)(lT[m] + es * 64);
      const int swz = (es & 7) << 4;
      if (sv >= 0) {
        const int node = m ? nid_r[gs] : sv;
        const float4* fp = (const float4*)((m ? qual : feat) + (size_t)node * 64 + hf * 32);
#pragma unroll
        for (int c = 0; c < 4; ++c) {
          float4 v0 = fp[2 * c], v1 = fp[2 * c + 1];
          uint4 pk = make_uint4(pk2(v0.x, v0.y), pk2(v0.z, v0.w),
                                pk2(v1.x, v1.y), pk2(v1.z, v1.w));
          *(uint4*)(dp + ((hf * 64 + c * 16) ^ swz)) = pk;
        }
      } else {
        uint4 z = make_uint4(0, 0, 0, 0);
#pragma unroll
        for (int c = 0; c < 4; ++c) *(uint4*)(dp + ((hf * 64 + c * 16) ^ swz)) = z;
      }
    }
    __syncthreads();

    // ---- 4 edge-tiles of 16: feat and qual accumulate into the SAME acc ----
#pragma unroll
    for (int et = 0; et < 4; ++et) {
      const int row = et * 16 + (lane & 15);
      const int rb = row * 128;
      const int swz = (row & 7) << 4;
      const int k0 = (lane >> 4) * 16;
      bf16x8 aS0 = *(const bf16x8*)((const char*)lT[0] + rb + (k0 ^ swz));
      bf16x8 aS1 = *(const bf16x8*)((const char*)lT[0] + rb + ((k0 + 64) ^ swz));
      bf16x8 aQ0 = *(const bf16x8*)((const char*)lT[1] + rb + (k0 ^ swz));
      bf16x8 aQ1 = *(const bf16x8*)((const char*)lT[1] + rb + ((k0 + 64) ^ swz));
      f32x4 acc = {0.f, 0.f, 0.f, 0.f};
      acc = __builtin_amdgcn_mfma_f32_16x16x32_bf16(aS0, wS0, acc, 0, 0, 0);
      acc = __builtin_amdgcn_mfma_f32_16x16x32_bf16(aS1, wS1, acc, 0, 0, 0);
      acc = __builtin_amdgcn_mfma_f32_16x16x32_bf16(aQ0, wQ0, acc, 0, 0, 0);
      acc = __builtin_amdgcn_mfma_f32_16x16x32_bf16(aQ1, wQ1, acc, 0, 0, 0);

      // epilogue: D row=(lane>>4)*4+j (edge), col=lane&15; DPP 16-lane reduce (VALU-only)
      float p0, p1, p2, p3;
#pragma unroll
      for (int j = 0; j < 4; ++j) {
        float v = acc[j] + bias_l;
        v = v > 0.f ? v : 0.2f * v;           // leaky_relu
        float s = dpp_add16(v * attn_l);
        if (j == 0) p0 = s; else if (j == 1) p1 = s; else if (j == 2) p2 = s; else p3 = s;
      }
      const int sub = lane & 15;
      if (sub < 4) {
        float v = sub == 0 ? p0 : sub == 1 ? p1 : sub == 2 ? p2 : p3;
        comb[wid][sb * 64 + et * 16 + (lane >> 4) * 4 + sub] = v;
      }
    }
    __syncthreads();
  }

  // ---- combine waves -> write scores directly in dst-sorted order ----
  {
    const int slot = tid >> 1;
    const int h = tid & 1;
    const int gs = base + slot;
    if (src_r[gs] >= 0) {
      scores2[(size_t)dpos_r[gs] * 2 + h] = comb[h * 2][slot] + comb[h * 2 + 1][slot];
    }
  }
}

// ---------------- aggregation: one wave per dst node, lane-parallel edge metadata --------------
__global__ __launch_bounds__(256) void agg_k(
    const float* __restrict__ feat, const float* __restrict__ scores2,
    const int* __restrict__ src_d, const int* __restrict__ excl,
    const int* __restrict__ partials, float* __restrict__ out, int N, int E) {
  const int lane = threadIdx.x & 63;
  const int wid = threadIdx.x >> 6;
  const int n = rfl(blockIdx.x * 4 + wid);
  if (n >= N) return;
  const int beg = excl[n] + partials[n >> 10];
  const int end = (n + 1 < N) ? (excl[n + 1] + partials[(n + 1) >> 10]) : E;
  const int cnt = end - beg;
  float o0 = 0.f, o1 = 0.f;
  if (cnt > 0) {
    const float2* sc2 = (const float2*)scores2;
    float m0 = -3.4e38f, m1 = -3.4e38f;
    for (int i = lane; i < cnt; i += 64) {
      const float2 s = sc2[beg + i];
      m0 = fmaxf(m0, s.x);
      m1 = fmaxf(m1, s.y);
    }
#pragma unroll
    for (int off = 32; off; off >>= 1) {
      m0 = fmaxf(m0, __shfl_xor(m0, off));
      m1 = fmaxf(m1, __shfl_xor(m1, off));
    }
    float A0 = 0.f, A1 = 0.f, d0 = 0.f, d1 = 0.f;
    for (int c0 = 0; c0 < cnt; c0 += 64) {
      const int i = c0 + lane;
      const bool val = i < cnt;
      const int idx = beg + (val ? i : 0);
      const float2 s = sc2[idx];           // contiguous (dst-sorted)
      const int sl = src_d[idx];           // contiguous (dst-sorted)
      const float z0 = val ? __expf(s.x - m0) : 0.f;
      const float z1 = val ? __expf(s.y - m1) : 0.f;
      d0 += z0;
      d1 += z1;
      const int kmax = min(64, cnt - c0);
#pragma unroll 4
      for (int k = 0; k < kmax; ++k) {
        const int ss = __builtin_amdgcn_readlane(sl, k);
        const float w0 = __int_as_float(__builtin_amdgcn_readlane(__float_as_int(z0), k));
        const float w1 = __int_as_float(__builtin_amdgcn_readlane(__float_as_int(z1), k));
        const float f = feat[(size_t)ss * 64 + lane];
        A0 = fmaf(f, w0, A0);
        A1 = fmaf(f, w1, A1);
      }
    }
#pragma unroll
    for (int off = 32; off; off >>= 1) {
      d0 += __shfl_xor(d0, off);
      d1 += __shfl_xor(d1, off);
    }
    o0 = A0 / d0;
    o1 = A1 / d1;
  }
  out[(size_t)n * 128 + lane] = o0;
  out[(size_t)n * 128 + 64 + lane] = o1;
}

extern "C" void kernel_launch(void* const* d_in, const int* in_sizes, int n_in,
                              void* d_out, int out_size, void* d_ws, size_t ws_size,
                              hipStream_t stream) {
  const float* feat  = (const float*)d_in[0];
  const float* Wsrc  = (const float*)d_in[1];
  const float* bsrc  = (const float*)d_in[2];
  const float* qual  = (const float*)d_in[3];
  const float* Wqual = (const float*)d_in[4];
  const float* bqual = (const float*)d_in[5];
  const float* attn  = (const float*)d_in[6];
  const int* src = (const int*)d_in[7];
  const int* dst = (const int*)d_in[8];
  const int* rt  = (const int*)d_in[9];
  const int* nid = (const int*)d_in[10];
  float* out = (float*)d_out;

  const int N = in_sizes[0] / 64;
  const int E = in_sizes[7];
  const int nb = (N + 1023) / 1024;
  const int EP = ((E + 1024) + 127) & ~127;   // padded r-sorted capacity

  char* p = (char*)d_ws;
  int* cnt_dst = (int*)p;      p += (size_t)N * 4;
  int* cnt_r = (int*)p;        p += 16 * 4;          // contiguous with cnt_dst for one memset
  int* excl = (int*)p;         p += (size_t)N * 4;
  int* cursor_dst = (int*)p;   p += (size_t)N * 4;
  int* poffs = (int*)p;        p += 16 * 4;
  int* cursor_r = (int*)p;     p += 16 * 4;
  int* partials = (int*)p;     p += (size_t)((nb + 15) & ~15) * 4;
  int* src_r = (int*)p;        p += (size_t)EP * 4;
  int* nid_r = (int*)p;        p += (size_t)EP * 4;
  int* dpos_r = (int*)p;       p += (size_t)EP * 4;
  int* src_d = (int*)p;        p += (size_t)E * 4;
  ushort* Wt = (ushort*)p;     p += 2 * 8 * 64 * 64 * 2;   // 128 KB bf16
  float* scores2 = (float*)p;  p += (size_t)E * 2 * 4;
  if ((size_t)(p - (char*)d_ws) > ws_size) return;   // workspace too small: bail visibly

  hipMemsetAsync(cnt_dst, 0, (size_t)(N + 16) * 4, stream);
  hipMemsetAsync(src_r, 0xFF, (size_t)EP * 4, stream);     // -1 sentinels for bucket padding

  const int histB = (E + 1023) / 1024;
  hist_k<<<histB + 4, 1024, 0, stream>>>(dst, rt, cnt_dst, cnt_r, E, histB, Wsrc, Wqual, Wt);
  scan_a<<<nb, 1024, 0, stream>>>(cnt_dst, excl, cursor_dst, partials, N);
  scan_b<<<1, 64, 0, stream>>>(partials, nb, cnt_r, poffs, cursor_r);
  scatter_k<<<(E + 1023) / 1024, 1024, 0, stream>>>(src, dst, rt, nid,
                                                    cursor_dst, partials, cursor_r,
                                                    src_r, nid_r, dpos_r, src_d, E);
  score_k<<<EP / 128, 256, 0, stream>>>(feat, qual, Wt, bsrc, bqual, attn,
                                        src_r, nid_r, dpos_r, poffs, scores2);
  agg_k<<<(N + 3) / 4, 256, 0, stream>>>(feat, scores2, src_d, excl, partials, out, N, E);
}

// Round 5
// 203.425 us; speedup vs baseline: 5.2122x; 1.2691x over previous
//
#include <hip/hip_runtime.h>
#include <hip/hip_bf16.h>
#include <cstdint>

// HEARConv: relation-projected edge attention + edge-softmax + weighted aggregation.
// Pipeline: hist(+Wtrans+bf16 table conv) -> scan_a -> scan_b -> scatter -> score(MFMA) -> agg.
// Round 5: feat/qual pre-converted to bf16 tables; all per-edge row gathers fetch 128 B not 256 B.

__device__ __forceinline__ int rfl(int v) { return __builtin_amdgcn_readfirstlane(v); }

typedef __attribute__((ext_vector_type(8))) short bf16x8;
typedef __attribute__((ext_vector_type(4))) float f32x4;

// pack two f32 -> two bf16 (round-half-up; <=1ulp vs RNE, threshold is 4.2e-2)
__device__ __forceinline__ uint32_t pk2(float a, float b) {
  uint32_t ua = __float_as_uint(a) + 0x8000u;
  uint32_t ub = __float_as_uint(b) + 0x8000u;
  return __builtin_amdgcn_perm(ub, ua, 0x07060302u);  // {ua.b2,ua.b3,ub.b2,ub.b3}
}

// sum across each 16-lane row via DPP row_ror (VALU-only, no LDS pipe)
__device__ __forceinline__ float dpp_add16(float x) {
  float s = x;
  int t;
  t = __builtin_amdgcn_update_dpp(0, __float_as_int(s), 0x128, 0xF, 0xF, true);
  s += __int_as_float(t);
  t = __builtin_amdgcn_update_dpp(0, __float_as_int(s), 0x124, 0xF, 0xF, true);
  s += __int_as_float(t);
  t = __builtin_amdgcn_update_dpp(0, __float_as_int(s), 0x122, 0xF, 0xF, true);
  s += __int_as_float(t);
  t = __builtin_amdgcn_update_dpp(0, __float_as_int(s), 0x121, 0xF, 0xF, true);
  s += __int_as_float(t);
  return s;
}

// ---------------- histogram (+ fused W transpose + feat/qual bf16 conversion) ------------------
// Wt layout: [m][r][col][k] bf16  (m: 0=Wsrc, 1=Wqual), so B-fragments load as 16B vectors.
__global__ void hist_k(const int* __restrict__ dst, const int* __restrict__ rt,
                       int* __restrict__ cnt_dst, int* __restrict__ cnt_r, int E, int histB,
                       const float* __restrict__ Wsrc, const float* __restrict__ Wqual,
                       ushort* __restrict__ Wt,
                       const float* __restrict__ feat, const float* __restrict__ qual,
                       ushort* __restrict__ feat_bf, ushort* __restrict__ qual_bf,
                       long tabElems) {
  if ((int)blockIdx.x >= histB + 4) {
    // ---- bf16 table conversion: 8 elements per thread ----
    const long gt = (long)(blockIdx.x - histB - 4) * 1024 + threadIdx.x;
    const long be = gt * 8;
    if (be < 2 * tabElems) {
      const int m = be >= tabElems;
      const long off = be - (m ? tabElems : 0);
      const float* s = (m ? qual : feat) + off;
      uint32_t o[4];
#pragma unroll
      for (int i = 0; i < 4; ++i) o[i] = pk2(s[2 * i], s[2 * i + 1]);
      *(uint4*)((m ? qual_bf : feat_bf) + off) = make_uint4(o[0], o[1], o[2], o[3]);
    }
    return;
  }
  if ((int)blockIdx.x >= histB) {
    // ---- W transpose to bf16 [m][r][col][k] ----
    const int gt = (blockIdx.x - histB) * 1024 + threadIdx.x;  // 0..4095
    const int m = gt >> 11;
    const int r = (gt >> 8) & 7;
    const int col = (gt >> 2) & 63;
    const int k0 = (gt & 3) * 16;
    const float* W = (m ? Wqual : Wsrc) + (size_t)r * 4096;
    uint32_t o[8];
#pragma unroll
    for (int i = 0; i < 8; ++i) {
      float a = W[(k0 + 2 * i) * 64 + col];
      float b = W[(k0 + 2 * i + 1) * 64 + col];
      o[i] = pk2(a, b);
    }
    ushort* d = Wt + ((((size_t)m * 8 + r) * 64 + col) * 64 + k0);
    *(uint4*)d = make_uint4(o[0], o[1], o[2], o[3]);
    *(uint4*)(d + 8) = make_uint4(o[4], o[5], o[6], o[7]);
    return;
  }
  __shared__ int hr[8];
  int tid = threadIdx.x;
  if (tid < 8) hr[tid] = 0;
  __syncthreads();
  int e = blockIdx.x * blockDim.x + tid;
  if (e < E) {
    atomicAdd(&cnt_dst[dst[e]], 1);
    atomicAdd(&hr[rt[e]], 1);
  }
  __syncthreads();
  if (tid < 8 && hr[tid] > 0) atomicAdd(&cnt_r[tid], hr[tid]);
}

// ---------------- scan phase A: per-1024 block exclusive scan, block totals -> partials --------
__global__ void scan_a(const int* __restrict__ cnt, int* __restrict__ excl,
                       int* __restrict__ cursor, int* __restrict__ partials, int n) {
  __shared__ int wsum[16];
  __shared__ int wbase[16];
  int tid = threadIdx.x;
  int g = blockIdx.x * 1024 + tid;
  int v = (g < n) ? cnt[g] : 0;
  int x = v;
#pragma unroll
  for (int off = 1; off < 64; off <<= 1) {
    int y = __shfl_up(x, off);
    if ((tid & 63) >= off) x += y;
  }
  if ((tid & 63) == 63) wsum[tid >> 6] = x;
  __syncthreads();
  if (tid == 0) {
    int run = 0;
#pragma unroll
    for (int w = 0; w < 16; ++w) { wbase[w] = run; run += wsum[w]; }
    partials[blockIdx.x] = run;
  }
  __syncthreads();
  int ex = x - v + wbase[tid >> 6];
  if (g < n) { excl[g] = ex; cursor[g] = ex; }
}

// ---------------- scan phase B: wave-parallel scan of partials + padded relation offsets -------
__global__ void scan_b(int* __restrict__ partials, int nb,
                       const int* __restrict__ cnt_r, int* __restrict__ poffs,
                       int* __restrict__ cursor_r) {
  const int lane = threadIdx.x;   // 64 threads
  int run = 0;
  for (int b0 = 0; b0 < nb; b0 += 64) {
    int i = b0 + lane;
    int v = (i < nb) ? partials[i] : 0;
    int x = v;
#pragma unroll
    for (int off = 1; off < 64; off <<= 1) {
      int y = __shfl_up(x, off);
      if (lane >= off) x += y;
    }
    if (i < nb) partials[i] = run + x - v;
    run += __shfl(x, 63);
  }
  if (lane == 0) {
    int pp = 0;
    for (int r = 0; r < 8; ++r) {
      poffs[r] = pp;
      cursor_r[r] = pp;
      pp += (cnt_r[r] + 127) & ~127;
    }
    poffs[8] = pp;
  }
}

// ---------------- scatter: r-sorted {src,nid,dpos} arrays + dst-sorted {src} array -------------
__global__ void scatter_k(const int* __restrict__ src, const int* __restrict__ dst,
                          const int* __restrict__ rt, const int* __restrict__ nid,
                          int* __restrict__ cursor_dst, const int* __restrict__ partials,
                          int* __restrict__ cursor_r,
                          int* __restrict__ src_r, int* __restrict__ nid_r,
                          int* __restrict__ dpos_r, int* __restrict__ src_d, int E) {
  __shared__ int hr[8], baser[8];
  int tid = threadIdx.x;
  if (tid < 8) hr[tid] = 0;
  __syncthreads();
  int e = blockIdx.x * blockDim.x + tid;
  int r = 0, lpos = 0;
  if (e < E) {
    r = rt[e];
    lpos = atomicAdd(&hr[r], 1);
  }
  __syncthreads();
  if (tid < 8) baser[tid] = hr[tid] ? atomicAdd(&cursor_r[tid], hr[tid]) : 0;
  __syncthreads();
  if (e < E) {
    const int p_r = baser[r] + lpos;
    const int d = dst[e];
    const int p_d = atomicAdd(&cursor_dst[d], 1) + partials[d >> 10];
    const int s = src[e];
    src_r[p_r] = s;
    nid_r[p_r] = nid[e];
    dpos_r[p_r] = p_d;
    src_d[p_d] = s;
  }
}

// ---------------- score kernel: MFMA gather-GEMM over relation buckets -------------------------
// Block = 256 threads, 128 edges of ONE relation, processed as 2 sub-batches of 64 edges
// through a single 16KB LDS buffer. Gathers read the PRE-CONVERTED bf16 tables (128 B rows).
__global__ __launch_bounds__(256, 8) void score_k(
    const ushort* __restrict__ feat_bf, const ushort* __restrict__ qual_bf,
    const ushort* __restrict__ Wt,
    const float* __restrict__ bsrc, const float* __restrict__ bqual,
    const float* __restrict__ attn,
    const int* __restrict__ src_r, const int* __restrict__ nid_r,
    const int* __restrict__ dpos_r,
    const int* __restrict__ poffs, float* __restrict__ scores2) {
  __shared__ __align__(16) ushort lT[2][64 * 64];   // [feat|qual][edge 0..63][k], 16 KB
  __shared__ float comb[4][128];                    // per-wave partial scores, 2 KB

  const int tid = threadIdx.x;
  const int lane = tid & 63;
  const int wid = tid >> 6;
  const int base = blockIdx.x * 128;
  if (base >= poffs[8]) return;
  int r = 0;
  while (base >= poffs[r + 1]) ++r;

  // B fragments: col = wid*16 + lane&15, k = (lane>>4)*8 + j  (coalesced 16B from Wt)
  const int col = wid * 16 + (lane & 15);
  const int kb = (lane >> 4) * 8;
  const ushort* WtS = Wt + ((size_t)r * 64 + col) * 64;
  const ushort* WtQ = Wt + (((size_t)8 + r) * 64 + col) * 64;
  const bf16x8 wS0 = *(const bf16x8*)(WtS + kb);
  const bf16x8 wS1 = *(const bf16x8*)(WtS + 32 + kb);
  const bf16x8 wQ0 = *(const bf16x8*)(WtQ + kb);
  const bf16x8 wQ1 = *(const bf16x8*)(WtQ + 32 + kb);
  const float bias_l = bsrc[r * 64 + col] + bqual[r * 64 + col];
  const float attn_l = attn[r * 64 + col];

  for (int sb = 0; sb < 2; ++sb) {
    // ---- stage 64 edges: straight 16B bf16 copies (half a 128B row per thread) ----
    {
      const int m = tid >> 7;          // 0 = feat, 1 = qual
      const int es = (tid >> 1) & 63;  // edge slot in sub-batch
      const int hf = tid & 1;          // row half
      const int gs = base + sb * 64 + es;
      const int sv = src_r[gs];
      char* dp = (char*)(lT[m] + es * 64);
      const int swz = (es & 7) << 4;
      if (sv >= 0) {
        const int node = m ? nid_r[gs] : sv;
        const char* gp = (const char*)(m ? qual_bf : feat_bf) + (size_t)node * 128 + hf * 64;
#pragma unroll
        for (int c = 0; c < 4; ++c)
          *(uint4*)(dp + ((hf * 64 + c * 16) ^ swz)) = *(const uint4*)(gp + c * 16);
      } else {
        uint4 z = make_uint4(0, 0, 0, 0);
#pragma unroll
        for (int c = 0; c < 4; ++c) *(uint4*)(dp + ((hf * 64 + c * 16) ^ swz)) = z;
      }
    }
    __syncthreads();

    // ---- 4 edge-tiles of 16: feat and qual accumulate into the SAME acc ----
#pragma unroll
    for (int et = 0; et < 4; ++et) {
      const int row = et * 16 + (lane & 15);
      const int rb = row * 128;
      const int swz = (row & 7) << 4;
      const int k0 = (lane >> 4) * 16;
      bf16x8 aS0 = *(const bf16x8*)((const char*)lT[0] + rb + (k0 ^ swz));
      bf16x8 aS1 = *(const bf16x8*)((const char*)lT[0] + rb + ((k0 + 64) ^ swz));
      bf16x8 aQ0 = *(const bf16x8*)((const char*)lT[1] + rb + (k0 ^ swz));
      bf16x8 aQ1 = *(const bf16x8*)((const char*)lT[1] + rb + ((k0 + 64) ^ swz));
      f32x4 acc = {0.f, 0.f, 0.f, 0.f};
      acc = __builtin_amdgcn_mfma_f32_16x16x32_bf16(aS0, wS0, acc, 0, 0, 0);
      acc = __builtin_amdgcn_mfma_f32_16x16x32_bf16(aS1, wS1, acc, 0, 0, 0);
      acc = __builtin_amdgcn_mfma_f32_16x16x32_bf16(aQ0, wQ0, acc, 0, 0, 0);
      acc = __builtin_amdgcn_mfma_f32_16x16x32_bf16(aQ1, wQ1, acc, 0, 0, 0);

      // epilogue: D row=(lane>>4)*4+j (edge), col=lane&15; DPP 16-lane reduce (VALU-only)
      float p0, p1, p2, p3;
#pragma unroll
      for (int j = 0; j < 4; ++j) {
        float v = acc[j] + bias_l;
        v = v > 0.f ? v : 0.2f * v;           // leaky_relu
        float s = dpp_add16(v * attn_l);
        if (j == 0) p0 = s; else if (j == 1) p1 = s; else if (j == 2) p2 = s; else p3 = s;
      }
      const int sub = lane & 15;
      if (sub < 4) {
        float v = sub == 0 ? p0 : sub == 1 ? p1 : sub == 2 ? p2 : p3;
        comb[wid][sb * 64 + et * 16 + (lane >> 4) * 4 + sub] = v;
      }
    }
    __syncthreads();
  }

  // ---- combine waves -> write scores directly in dst-sorted order ----
  {
    const int slot = tid >> 1;
    const int h = tid & 1;
    const int gs = base + slot;
    if (src_r[gs] >= 0) {
      scores2[(size_t)dpos_r[gs] * 2 + h] = comb[h * 2][slot] + comb[h * 2 + 1][slot];
    }
  }
}

// ---------------- aggregation: one wave per dst node, bf16 feat gathers ------------------------
__global__ __launch_bounds__(256) void agg_k(
    const ushort* __restrict__ feat_bf, const float* __restrict__ scores2,
    const int* __restrict__ src_d, const int* __restrict__ excl,
    const int* __restrict__ partials, float* __restrict__ out, int N, int E) {
  const int lane = threadIdx.x & 63;
  const int wid = threadIdx.x >> 6;
  const int n = rfl(blockIdx.x * 4 + wid);
  if (n >= N) return;
  const int beg = excl[n] + partials[n >> 10];
  const int end = (n + 1 < N) ? (excl[n + 1] + partials[(n + 1) >> 10]) : E;
  const int cnt = end - beg;
  float o0 = 0.f, o1 = 0.f;
  if (cnt > 0) {
    const float2* sc2 = (const float2*)scores2;
    float m0 = -3.4e38f, m1 = -3.4e38f;
    for (int i = lane; i < cnt; i += 64) {
      const float2 s = sc2[beg + i];
      m0 = fmaxf(m0, s.x);
      m1 = fmaxf(m1, s.y);
    }
#pragma unroll
    for (int off = 32; off; off >>= 1) {
      m0 = fmaxf(m0, __shfl_xor(m0, off));
      m1 = fmaxf(m1, __shfl_xor(m1, off));
    }
    float A0 = 0.f, A1 = 0.f, d0 = 0.f, d1 = 0.f;
    for (int c0 = 0; c0 < cnt; c0 += 64) {
      const int i = c0 + lane;
      const bool val = i < cnt;
      const int idx = beg + (val ? i : 0);
      const float2 s = sc2[idx];           // contiguous (dst-sorted)
      const int sl = src_d[idx];           // contiguous (dst-sorted)
      const float z0 = val ? __expf(s.x - m0) : 0.f;
      const float z1 = val ? __expf(s.y - m1) : 0.f;
      d0 += z0;
      d1 += z1;
      const int kmax = min(64, cnt - c0);
#pragma unroll 4
      for (int k = 0; k < kmax; ++k) {
        const int ss = __builtin_amdgcn_readlane(sl, k);
        const float w0 = __int_as_float(__builtin_amdgcn_readlane(__float_as_int(z0), k));
        const float w1 = __int_as_float(__builtin_amdgcn_readlane(__float_as_int(z1), k));
        const float f = __uint_as_float((uint32_t)feat_bf[(size_t)ss * 64 + lane] << 16);
        A0 = fmaf(f, w0, A0);
        A1 = fmaf(f, w1, A1);
      }
    }
#pragma unroll
    for (int off = 32; off; off >>= 1) {
      d0 += __shfl_xor(d0, off);
      d1 += __shfl_xor(d1, off);
    }
    o0 = A0 / d0;
    o1 = A1 / d1;
  }
  out[(size_t)n * 128 + lane] = o0;
  out[(size_t)n * 128 + 64 + lane] = o1;
}

extern "C" void kernel_launch(void* const* d_in, const int* in_sizes, int n_in,
                              void* d_out, int out_size, void* d_ws, size_t ws_size,
                              hipStream_t stream) {
  const float* feat  = (const float*)d_in[0];
  const float* Wsrc  = (const float*)d_in[1];
  const float* bsrc  = (const float*)d_in[2];
  const float* qual  = (const float*)d_in[3];
  const float* Wqual = (const float*)d_in[4];
  const float* bqual = (const float*)d_in[5];
  const float* attn  = (const float*)d_in[6];
  const int* src = (const int*)d_in[7];
  const int* dst = (const int*)d_in[8];
  const int* rt  = (const int*)d_in[9];
  const int* nid = (const int*)d_in[10];
  float* out = (float*)d_out;

  const int N = in_sizes[0] / 64;
  const int E = in_sizes[7];
  const long tabElems = (long)N * 64;
  const int nb = (N + 1023) / 1024;
  const int EP = ((E + 1024) + 127) & ~127;   // padded r-sorted capacity

  char* p = (char*)d_ws;
  int* cnt_dst = (int*)p;      p += (size_t)N * 4;
  int* cnt_r = (int*)p;        p += 16 * 4;          // contiguous with cnt_dst for one memset
  int* excl = (int*)p;         p += (size_t)N * 4;
  int* cursor_dst = (int*)p;   p += (size_t)N * 4;
  int* poffs = (int*)p;        p += 16 * 4;
  int* cursor_r = (int*)p;     p += 16 * 4;
  int* partials = (int*)p;     p += (size_t)((nb + 15) & ~15) * 4;
  int* src_r = (int*)p;        p += (size_t)EP * 4;
  int* nid_r = (int*)p;        p += (size_t)EP * 4;
  int* dpos_r = (int*)p;       p += (size_t)EP * 4;
  int* src_d = (int*)p;        p += (size_t)E * 4;
  ushort* Wt = (ushort*)p;     p += 2 * 8 * 64 * 64 * 2;   // 128 KB bf16
  ushort* feat_bf = (ushort*)p; p += (size_t)tabElems * 2;
  ushort* qual_bf = (ushort*)p; p += (size_t)tabElems * 2;
  float* scores2 = (float*)p;  p += (size_t)E * 2 * 4;
  if ((size_t)(p - (char*)d_ws) > ws_size) return;   // workspace too small: bail visibly

  hipMemsetAsync(cnt_dst, 0, (size_t)(N + 16) * 4, stream);
  hipMemsetAsync(src_r, 0xFF, (size_t)EP * 4, stream);     // -1 sentinels for bucket padding

  const int histB = (E + 1023) / 1024;
  const int convB = (int)((2 * tabElems / 8 + 1023) / 1024);
  hist_k<<<histB + 4 + convB, 1024, 0, stream>>>(dst, rt, cnt_dst, cnt_r, E, histB,
                                                 Wsrc, Wqual, Wt,
                                                 feat, qual, feat_bf, qual_bf, tabElems);
  scan_a<<<nb, 1024, 0, stream>>>(cnt_dst, excl, cursor_dst, partials, N);
  scan_b<<<1, 64, 0, stream>>>(partials, nb, cnt_r, poffs, cursor_r);
  scatter_k<<<(E + 1023) / 1024, 1024, 0, stream>>>(src, dst, rt, nid,
                                                    cursor_dst, partials, cursor_r,
                                                    src_r, nid_r, dpos_r, src_d, E);
  score_k<<<EP / 128, 256, 0, stream>>>(feat_bf, qual_bf, Wt, bsrc, bqual, attn,
                                        src_r, nid_r, dpos_r, poffs, scores2);
  agg_k<<<(N + 3) / 4, 256, 0, stream>>>(feat_bf, scores2, src_d, excl, partials, out, N, E);
}